// Round 1
// baseline (1004.406 us; speedup 1.0000x reference)
//
#include <hip/hip_runtime.h>
#include <hip/hip_bf16.h>

#define N_NODES 100000
#define N_EDGES 1600000
#define IN_DIM 128
#define HID 64

// ---------------- degree histogram ----------------
__global__ __launch_bounds__(256) void k_hist(const int* __restrict__ dst,
                                              int* __restrict__ counts) {
  int i = blockIdx.x * 256 + threadIdx.x;
  if (i < N_EDGES) atomicAdd(&counts[dst[i]], 1);
}

__global__ __launch_bounds__(256) void k_dinv(const int* __restrict__ counts,
                                              float* __restrict__ dinv) {
  int i = blockIdx.x * 256 + threadIdx.x;
  if (i < N_NODES) dinv[i] = rsqrtf((float)counts[i] + 1.0f);
}

// ---------------- hierarchical exclusive scan (chunk = 1024) ----------------
__global__ __launch_bounds__(256) void k_scan1(const int* __restrict__ counts,
                                               int* __restrict__ offs,
                                               int* __restrict__ bsum) {
  __shared__ int lds[256];
  int t = threadIdx.x;
  int idx0 = blockIdx.x * 1024 + t * 4;
  int c[4];
#pragma unroll
  for (int j = 0; j < 4; ++j) {
    int idx = idx0 + j;
    c[j] = (idx < N_NODES) ? counts[idx] : 0;
  }
  int tsum = c[0] + c[1] + c[2] + c[3];
  int val = tsum;
  lds[t] = val;
  __syncthreads();
  for (int off = 1; off < 256; off <<= 1) {
    int u = (t >= off) ? lds[t - off] : 0;
    __syncthreads();
    val += u;
    lds[t] = val;
    __syncthreads();
  }
  int excl = val - tsum;  // exclusive prefix of this thread within block
#pragma unroll
  for (int j = 0; j < 4; ++j) {
    int idx = idx0 + j;
    if (idx < N_NODES) offs[idx] = excl;
    excl += c[j];
  }
  if (t == 255) bsum[blockIdx.x] = val;  // block total
}

__global__ __launch_bounds__(128) void k_scan2(int* __restrict__ bsum, int nblk) {
  __shared__ int lds[128];
  int t = threadIdx.x;
  int orig = (t < nblk) ? bsum[t] : 0;
  int val = orig;
  lds[t] = val;
  __syncthreads();
  for (int off = 1; off < 128; off <<= 1) {
    int u = (t >= off) ? lds[t - off] : 0;
    __syncthreads();
    val += u;
    lds[t] = val;
    __syncthreads();
  }
  if (t < nblk) bsum[t] = val - orig;  // exclusive
}

__global__ __launch_bounds__(256) void k_scan3(int* __restrict__ offs,
                                               int* __restrict__ cursor,
                                               const int* __restrict__ bsum) {
  int t = threadIdx.x;
  int add = bsum[blockIdx.x];
  int idx0 = blockIdx.x * 1024 + t * 4;
#pragma unroll
  for (int j = 0; j < 4; ++j) {
    int idx = idx0 + j;
    if (idx < N_NODES) {
      int v = offs[idx] + add;
      offs[idx] = v;
      cursor[idx] = v;
    }
  }
  if (blockIdx.x == 0 && t == 0) offs[N_NODES] = N_EDGES;
}

// ---------------- CSR fill ----------------
__global__ __launch_bounds__(256) void k_fill(const int* __restrict__ ei,
                                              int* __restrict__ cursor,
                                              int* __restrict__ csr_src) {
  int i = blockIdx.x * 256 + threadIdx.x;
  if (i < N_EDGES) {
    int s = ei[i];
    int d = ei[N_EDGES + i];
    int p = atomicAdd(&cursor[d], 1);
    csr_src[p] = s;
  }
}

// ---------------- pre GEMM: [N,128] @ [128,64] + b ----------------
__global__ __launch_bounds__(256) void k_pre_gemm(const float* __restrict__ x,
                                                  const float* __restrict__ W,
                                                  const float* __restrict__ b,
                                                  float* __restrict__ out) {
  __shared__ float Ws[IN_DIM * HID];
  __shared__ float bs[HID];
  for (int i = threadIdx.x; i < IN_DIM * HID / 4; i += 256)
    ((float4*)Ws)[i] = ((const float4*)W)[i];
  if (threadIdx.x < HID) bs[threadIdx.x] = b[threadIdx.x];
  __syncthreads();
  int f = threadIdx.x & 63;
  int row = blockIdx.x * 4 + (threadIdx.x >> 6);
  float xv0 = x[row * IN_DIM + f];
  float xv1 = x[row * IN_DIM + 64 + f];
  float acc = bs[f];
#pragma unroll
  for (int k = 0; k < 64; ++k) {
    acc += __shfl(xv0, k) * Ws[k * HID + f];
    acc += __shfl(xv1, k) * Ws[(k + 64) * HID + f];
  }
  out[row * HID + f] = acc;
}

// ---------------- hidden GEMM: [N,64] @ [64,64] (no bias) ----------------
__global__ __launch_bounds__(256) void k_gemm64(const float* __restrict__ h,
                                                const float* __restrict__ W,
                                                float* __restrict__ out) {
  __shared__ float Ws[HID * HID];
  for (int i = threadIdx.x; i < HID * HID / 4; i += 256)
    ((float4*)Ws)[i] = ((const float4*)W)[i];
  __syncthreads();
  int f = threadIdx.x & 63;
  int row = blockIdx.x * 4 + (threadIdx.x >> 6);
  float xv = h[row * HID + f];
  float acc = 0.0f;
#pragma unroll
  for (int k = 0; k < 64; ++k) acc += __shfl(xv, k) * Ws[k * HID + f];
  out[row * HID + f] = acc;
}

// ---------------- aggregation (wave per node, lane = feature) ----------------
// MODE 0: bias + relu      MODE 1: bias + L2 row-normalize (final layer)
template <int MODE>
__global__ __launch_bounds__(256) void k_agg(const float* __restrict__ hw,
                                             const int* __restrict__ offs,
                                             const int* __restrict__ csr_src,
                                             const float* __restrict__ dinv,
                                             const float* __restrict__ bias,
                                             float* __restrict__ out) {
  int node = blockIdx.x * 4 + (threadIdx.x >> 6);
  int f = threadIdx.x & 63;
  float di = dinv[node];
  int beg = offs[node];
  int end = offs[node + 1];
  float acc = hw[node * HID + f] * (di * di);  // self-loop term
  int e = beg;
  for (; e + 4 <= end; e += 4) {
    int s0 = csr_src[e + 0];
    int s1 = csr_src[e + 1];
    int s2 = csr_src[e + 2];
    int s3 = csr_src[e + 3];
    float w0 = dinv[s0] * di;
    float w1 = dinv[s1] * di;
    float w2 = dinv[s2] * di;
    float w3 = dinv[s3] * di;
    float h0 = hw[s0 * HID + f];
    float h1 = hw[s1 * HID + f];
    float h2 = hw[s2 * HID + f];
    float h3 = hw[s3 * HID + f];
    acc += h0 * w0 + h1 * w1 + h2 * w2 + h3 * w3;
  }
  for (; e < end; ++e) {
    int s = csr_src[e];
    acc += hw[s * HID + f] * (dinv[s] * di);
  }
  acc += bias[f];
  if (MODE == 0) acc = fmaxf(acc, 0.0f);
  if (MODE == 1) {
    float ss = acc * acc;
#pragma unroll
    for (int off = 32; off; off >>= 1) ss += __shfl_xor(ss, off);
    float scale = 1.0f / fmaxf(sqrtf(ss), 1e-12f);
    acc *= scale;
  }
  out[node * HID + f] = acc;
}

extern "C" void kernel_launch(void* const* d_in, const int* in_sizes, int n_in,
                              void* d_out, int out_size, void* d_ws, size_t ws_size,
                              hipStream_t stream) {
  const float* x     = (const float*)d_in[0];
  const int*   ei    = (const int*)d_in[1];   // [2, E] int32 (jax x64 disabled)
  const float* W_pre = (const float*)d_in[2];
  const float* b_pre = (const float*)d_in[3];
  const float* W1    = (const float*)d_in[4];
  const float* b1    = (const float*)d_in[5];
  const float* W2    = (const float*)d_in[6];
  const float* b2    = (const float*)d_in[7];
  const float* W3    = (const float*)d_in[8];
  const float* b3    = (const float*)d_in[9];
  float* out = (float*)d_out;

  char* ws = (char*)d_ws;
  float* bufA   = (float*)(ws + 0);                // 25.6 MB features
  float* hw     = (float*)(ws + 25600000);         // 25.6 MB gemm out
  int*   csr    = (int*)(ws + 51200000);           // 6.4 MB
  int*   counts = (int*)(ws + 57600000);           // 400 KB
  int*   offs   = (int*)(ws + 58000000);           // N+1 ints
  int*   cursor = (int*)(ws + 58400016);           // 400 KB
  float* dinv   = (float*)(ws + 58800016);         // 400 KB
  int*   bsum   = (int*)(ws + 59200016);           // scan partials

  const int NBLK = (N_NODES + 1023) / 1024;  // 98

  hipMemsetAsync(counts, 0, N_NODES * sizeof(int), stream);
  k_hist<<<(N_EDGES + 255) / 256, 256, 0, stream>>>(ei + N_EDGES, counts);
  k_dinv<<<(N_NODES + 255) / 256, 256, 0, stream>>>(counts, dinv);
  k_scan1<<<NBLK, 256, 0, stream>>>(counts, offs, bsum);
  k_scan2<<<1, 128, 0, stream>>>(bsum, NBLK);
  k_scan3<<<NBLK, 256, 0, stream>>>(offs, cursor, bsum);
  k_fill<<<(N_EDGES + 255) / 256, 256, 0, stream>>>(ei, cursor, csr);

  k_pre_gemm<<<N_NODES / 4, 256, 0, stream>>>(x, W_pre, b_pre, bufA);

  // layer 1
  k_gemm64<<<N_NODES / 4, 256, 0, stream>>>(bufA, W1, hw);
  k_agg<0><<<N_NODES / 4, 256, 0, stream>>>(hw, offs, csr, dinv, b1, bufA);
  // layer 2
  k_gemm64<<<N_NODES / 4, 256, 0, stream>>>(bufA, W2, hw);
  k_agg<0><<<N_NODES / 4, 256, 0, stream>>>(hw, offs, csr, dinv, b2, bufA);
  // layer 3 (no relu; fused L2 normalize)
  k_gemm64<<<N_NODES / 4, 256, 0, stream>>>(bufA, W3, hw);
  k_agg<1><<<N_NODES / 4, 256, 0, stream>>>(hw, offs, csr, dinv, b3, out);
}

// Round 3
// 598.866 us; speedup vs baseline: 1.6772x; 1.6772x over previous
//
#include <hip/hip_runtime.h>
#include <hip/hip_bf16.h>

#define N_NODES 100000
#define N_EDGES 1600000
#define IN_DIM 128
#define HID 64

typedef __attribute__((ext_vector_type(8))) _Float16 h8v;
typedef __attribute__((ext_vector_type(4))) float f4v;

// ---------------- degree histogram ----------------
__global__ __launch_bounds__(256) void k_hist(const int* __restrict__ dst,
                                              int* __restrict__ counts) {
  int i = blockIdx.x * 256 + threadIdx.x;
  if (i < N_EDGES) atomicAdd(&counts[dst[i]], 1);
}

__global__ __launch_bounds__(256) void k_dinv(const int* __restrict__ counts,
                                              float* __restrict__ dinv) {
  int i = blockIdx.x * 256 + threadIdx.x;
  if (i < N_NODES) dinv[i] = rsqrtf((float)counts[i] + 1.0f);
}

// ---------------- hierarchical exclusive scan (chunk = 1024) ----------------
__global__ __launch_bounds__(256) void k_scan1(const int* __restrict__ counts,
                                               int* __restrict__ offs,
                                               int* __restrict__ bsum) {
  __shared__ int lds[256];
  int t = threadIdx.x;
  int idx0 = blockIdx.x * 1024 + t * 4;
  int c[4];
#pragma unroll
  for (int j = 0; j < 4; ++j) {
    int idx = idx0 + j;
    c[j] = (idx < N_NODES) ? counts[idx] : 0;
  }
  int tsum = c[0] + c[1] + c[2] + c[3];
  int val = tsum;
  lds[t] = val;
  __syncthreads();
  for (int off = 1; off < 256; off <<= 1) {
    int u = (t >= off) ? lds[t - off] : 0;
    __syncthreads();
    val += u;
    lds[t] = val;
    __syncthreads();
  }
  int excl = val - tsum;
#pragma unroll
  for (int j = 0; j < 4; ++j) {
    int idx = idx0 + j;
    if (idx < N_NODES) offs[idx] = excl;
    excl += c[j];
  }
  if (t == 255) bsum[blockIdx.x] = val;
}

__global__ __launch_bounds__(128) void k_scan2(int* __restrict__ bsum, int nblk) {
  __shared__ int lds[128];
  int t = threadIdx.x;
  int orig = (t < nblk) ? bsum[t] : 0;
  int val = orig;
  lds[t] = val;
  __syncthreads();
  for (int off = 1; off < 128; off <<= 1) {
    int u = (t >= off) ? lds[t - off] : 0;
    __syncthreads();
    val += u;
    lds[t] = val;
    __syncthreads();
  }
  if (t < nblk) bsum[t] = val - orig;
}

__global__ __launch_bounds__(256) void k_scan3(int* __restrict__ offs,
                                               int* __restrict__ cursor,
                                               const int* __restrict__ bsum) {
  int t = threadIdx.x;
  int add = bsum[blockIdx.x];
  int idx0 = blockIdx.x * 1024 + t * 4;
#pragma unroll
  for (int j = 0; j < 4; ++j) {
    int idx = idx0 + j;
    if (idx < N_NODES) {
      int v = offs[idx] + add;
      offs[idx] = v;
      cursor[idx] = v;
    }
  }
  if (blockIdx.x == 0 && t == 0) offs[N_NODES] = N_EDGES;
}

// ---------------- CSR fill ----------------
__global__ __launch_bounds__(256) void k_fill(const int* __restrict__ ei,
                                              int* __restrict__ cursor,
                                              int* __restrict__ csr_src) {
  int i = blockIdx.x * 256 + threadIdx.x;
  if (i < N_EDGES) {
    int s = ei[i];
    int d = ei[N_EDGES + i];
    int p = atomicAdd(&cursor[d], 1);
    csr_src[p] = s;
  }
}

// ---------------- weight prep: split fp32 W[K][64] -> transposed half hi/lo [64][K] ----
__global__ __launch_bounds__(256) void k_prep_w(const float* __restrict__ W,
                                                _Float16* __restrict__ hi,
                                                _Float16* __restrict__ lo, int K) {
  int i = blockIdx.x * 256 + threadIdx.x;
  if (i < K * 64) {
    int k = i >> 6, n = i & 63;
    float v = W[i];
    _Float16 h = (_Float16)v;          // RTN
    float r = v - (float)h;            // exact residual
    hi[n * K + k] = h;
    lo[n * K + k] = (_Float16)r;
  }
}

// ---------------- MFMA GEMM: [N,K] fp32 @ Wt(half hi/lo) -> [N,64] fp32 ------------
// block = 256 (4 waves); wave computes 16 rows x 64 cols; no LDS.
// Split-fp16: out = xh*Wh + xl*Wh + xh*Wl  (error ~2^-22, fp32-equivalent here)
template <int K, bool BIAS>
__global__ __launch_bounds__(256) void k_gemm_mfma(const float* __restrict__ X,
                                                   const _Float16* __restrict__ Wh,
                                                   const _Float16* __restrict__ Wl,
                                                   const float* __restrict__ bias,
                                                   float* __restrict__ out) {
  int wave = threadIdx.x >> 6;
  int lane = threadIdx.x & 63;
  int fi = lane & 15;        // A: row-in-tile / B,C: col-in-tile
  int quad = lane >> 4;      // A,B: k-chunk / C: row-group
  int r0 = blockIdx.x * 64 + wave * 16;
  int row_l = r0 + fi;
  if (row_l >= N_NODES) row_l = N_NODES - 1;  // clamp loads; stores masked
  const float* xp = X + (size_t)row_l * K + quad * 8;

  f4v acc[4];
#pragma unroll
  for (int ct = 0; ct < 4; ++ct) acc[ct] = (f4v){0.f, 0.f, 0.f, 0.f};

#pragma unroll
  for (int k0 = 0; k0 < K; k0 += 32) {
    f4v xa = *(const f4v*)(xp + k0);
    f4v xb = *(const f4v*)(xp + k0 + 4);
    // split into hi/lo fp16 fragments (scalar casts -> v_cvt_f16_f32)
    h8v ah, al;
#pragma unroll
    for (int j = 0; j < 4; ++j) {
      _Float16 h = (_Float16)xa[j];
      ah[j] = h;
      al[j] = (_Float16)(xa[j] - (float)h);
    }
#pragma unroll
    for (int j = 0; j < 4; ++j) {
      _Float16 h = (_Float16)xb[j];
      ah[4 + j] = h;
      al[4 + j] = (_Float16)(xb[j] - (float)h);
    }

    const _Float16* whp = Wh + (size_t)fi * K + k0 + quad * 8;
    const _Float16* wlp = Wl + (size_t)fi * K + k0 + quad * 8;
#pragma unroll
    for (int ct = 0; ct < 4; ++ct) {
      h8v bh = *(const h8v*)(whp + (size_t)ct * 16 * K);
      h8v bl = *(const h8v*)(wlp + (size_t)ct * 16 * K);
      acc[ct] = __builtin_amdgcn_mfma_f32_16x16x32_f16(ah, bh, acc[ct], 0, 0, 0);
      acc[ct] = __builtin_amdgcn_mfma_f32_16x16x32_f16(al, bh, acc[ct], 0, 0, 0);
      acc[ct] = __builtin_amdgcn_mfma_f32_16x16x32_f16(ah, bl, acc[ct], 0, 0, 0);
    }
  }

  // epilogue: D[row = quad*4 + j][col = ct*16 + fi]
#pragma unroll
  for (int ct = 0; ct < 4; ++ct) {
    float bv = 0.f;
    if (BIAS) bv = bias[ct * 16 + fi];
#pragma unroll
    for (int j = 0; j < 4; ++j) {
      int orow = r0 + quad * 4 + j;
      if (orow < N_NODES) out[(size_t)orow * HID + ct * 16 + fi] = acc[ct][j] + bv;
    }
  }
}

// ---------------- aggregation: wave per node, quad-parallel, float4 per lane -------
// MODE 0: bias + relu      MODE 1: bias + L2 row-normalize (final layer)
template <int MODE>
__global__ __launch_bounds__(256) void k_agg(const float* __restrict__ hw,
                                             const int* __restrict__ offs,
                                             const int* __restrict__ csr_src,
                                             const float* __restrict__ dinv,
                                             const float* __restrict__ bias,
                                             float* __restrict__ out) {
  int node = blockIdx.x * 4 + (threadIdx.x >> 6);
  int lane = threadIdx.x & 63;
  int quad = lane >> 4;      // which neighbor in the group of 4
  int fi = lane & 15;        // which float4 chunk of the 64 features
  float di = dinv[node];
  int beg = offs[node];
  int end = offs[node + 1];

  f4v acc = {0.f, 0.f, 0.f, 0.f};
  if (quad == 0) {  // self-loop term
    f4v hv = *(const f4v*)(hw + (size_t)node * HID + fi * 4);
    acc = hv * (di * di);
  }
  for (int e = beg + quad; e < end; e += 4) {
    int s = csr_src[e];
    float w = dinv[s] * di;
    f4v hv = *(const f4v*)(hw + (size_t)s * HID + fi * 4);
    acc += hv * w;
  }
  // reduce across the 4 quads
#pragma unroll
  for (int c = 0; c < 4; ++c) {
    float v = acc[c];
    v += __shfl_xor(v, 16);
    v += __shfl_xor(v, 32);
    acc[c] = v;
  }
  if (quad == 0) {
    f4v bv = *(const f4v*)(bias + fi * 4);
    acc += bv;
    if (MODE == 0) {
#pragma unroll
      for (int c = 0; c < 4; ++c) acc[c] = fmaxf(acc[c], 0.f);
    } else {
      float ss = acc[0] * acc[0] + acc[1] * acc[1] + acc[2] * acc[2] + acc[3] * acc[3];
      ss += __shfl_xor(ss, 1);
      ss += __shfl_xor(ss, 2);
      ss += __shfl_xor(ss, 4);
      ss += __shfl_xor(ss, 8);
      float sc = 1.0f / fmaxf(sqrtf(ss), 1e-12f);
      acc *= sc;
    }
    *(f4v*)(out + (size_t)node * HID + fi * 4) = acc;
  }
}

extern "C" void kernel_launch(void* const* d_in, const int* in_sizes, int n_in,
                              void* d_out, int out_size, void* d_ws, size_t ws_size,
                              hipStream_t stream) {
  const float* x     = (const float*)d_in[0];
  const int*   ei    = (const int*)d_in[1];   // [2, E] int32
  const float* W_pre = (const float*)d_in[2];
  const float* b_pre = (const float*)d_in[3];
  const float* W1    = (const float*)d_in[4];
  const float* b1    = (const float*)d_in[5];
  const float* W2    = (const float*)d_in[6];
  const float* b2    = (const float*)d_in[7];
  const float* W3    = (const float*)d_in[8];
  const float* b3    = (const float*)d_in[9];
  float* out = (float*)d_out;

  char* ws = (char*)d_ws;
  float* bufA   = (float*)(ws + 0);                // 25.6 MB features
  float* hw     = (float*)(ws + 25600000);         // 25.6 MB gemm out
  int*   csr    = (int*)(ws + 51200000);           // 6.4 MB
  int*   counts = (int*)(ws + 57600000);           // 400 KB
  int*   offs   = (int*)(ws + 58000000);           // N+1 ints
  int*   cursor = (int*)(ws + 58400016);           // 400 KB
  float* dinv   = (float*)(ws + 58800016);         // 400 KB
  int*   bsum   = (int*)(ws + 59200016);           // scan partials (392 B)
  _Float16* WpreH = (_Float16*)(ws + 59400000);    // 64*128 half = 16 KB
  _Float16* WpreL = (_Float16*)(ws + 59416384);
  _Float16* W1H   = (_Float16*)(ws + 59432768);    // 64*64 half = 8 KB each
  _Float16* W1L   = (_Float16*)(ws + 59440960);
  _Float16* W2H   = (_Float16*)(ws + 59449152);
  _Float16* W2L   = (_Float16*)(ws + 59457344);
  _Float16* W3H   = (_Float16*)(ws + 59465536);
  _Float16* W3L   = (_Float16*)(ws + 59473728);

  const int NBLK = (N_NODES + 1023) / 1024;  // 98
  const int GEMM_BLOCKS = (N_NODES + 63) / 64;  // 1563

  hipMemsetAsync(counts, 0, N_NODES * sizeof(int), stream);
  k_hist<<<(N_EDGES + 255) / 256, 256, 0, stream>>>(ei + N_EDGES, counts);
  k_dinv<<<(N_NODES + 255) / 256, 256, 0, stream>>>(counts, dinv);
  k_scan1<<<NBLK, 256, 0, stream>>>(counts, offs, bsum);
  k_scan2<<<1, 128, 0, stream>>>(bsum, NBLK);
  k_scan3<<<NBLK, 256, 0, stream>>>(offs, cursor, bsum);
  k_fill<<<(N_EDGES + 255) / 256, 256, 0, stream>>>(ei, cursor, csr);

  k_prep_w<<<(IN_DIM * 64 + 255) / 256, 256, 0, stream>>>(W_pre, WpreH, WpreL, IN_DIM);
  k_prep_w<<<(HID * 64 + 255) / 256, 256, 0, stream>>>(W1, W1H, W1L, HID);
  k_prep_w<<<(HID * 64 + 255) / 256, 256, 0, stream>>>(W2, W2H, W2L, HID);
  k_prep_w<<<(HID * 64 + 255) / 256, 256, 0, stream>>>(W3, W3H, W3L, HID);

  k_gemm_mfma<IN_DIM, true><<<GEMM_BLOCKS, 256, 0, stream>>>(x, WpreH, WpreL, b_pre, bufA);

  // layer 1
  k_gemm_mfma<HID, false><<<GEMM_BLOCKS, 256, 0, stream>>>(bufA, W1H, W1L, nullptr, hw);
  k_agg<0><<<N_NODES / 4, 256, 0, stream>>>(hw, offs, csr, dinv, b1, bufA);
  // layer 2
  k_gemm_mfma<HID, false><<<GEMM_BLOCKS, 256, 0, stream>>>(bufA, W2H, W2L, nullptr, hw);
  k_agg<0><<<N_NODES / 4, 256, 0, stream>>>(hw, offs, csr, dinv, b2, bufA);
  // layer 3 (fused L2 normalize)
  k_gemm_mfma<HID, false><<<GEMM_BLOCKS, 256, 0, stream>>>(bufA, W3H, W3L, nullptr, hw);
  k_agg<1><<<N_NODES / 4, 256, 0, stream>>>(hw, offs, csr, dinv, b3, out);
}

// Round 4
// 501.905 us; speedup vs baseline: 2.0012x; 1.1932x over previous
//
#include <hip/hip_runtime.h>
#include <hip/hip_bf16.h>

#define N_NODES 100000
#define N_EDGES 1600000
#define IN_DIM 128
#define HID 64
#define NB 782               // ceil(100000 / 128) buckets of 128 nodes

typedef __attribute__((ext_vector_type(8))) _Float16 h8v;
typedef __attribute__((ext_vector_type(4))) float f4v;

// ---------------- degree histogram ----------------
__global__ __launch_bounds__(256) void k_hist(const int* __restrict__ dst,
                                              int* __restrict__ counts) {
  int i = blockIdx.x * 256 + threadIdx.x;
  if (i < N_EDGES) atomicAdd(&counts[dst[i]], 1);
}

__global__ __launch_bounds__(256) void k_dinv(const int* __restrict__ counts,
                                              float* __restrict__ dinv) {
  int i = blockIdx.x * 256 + threadIdx.x;
  if (i < N_NODES) dinv[i] = rsqrtf((float)counts[i] + 1.0f);
}

// ---------------- hierarchical exclusive scan (chunk = 1024) ----------------
__global__ __launch_bounds__(256) void k_scan1(const int* __restrict__ counts,
                                               int* __restrict__ offs,
                                               int* __restrict__ bsum) {
  __shared__ int lds[256];
  int t = threadIdx.x;
  int idx0 = blockIdx.x * 1024 + t * 4;
  int c[4];
#pragma unroll
  for (int j = 0; j < 4; ++j) {
    int idx = idx0 + j;
    c[j] = (idx < N_NODES) ? counts[idx] : 0;
  }
  int tsum = c[0] + c[1] + c[2] + c[3];
  int val = tsum;
  lds[t] = val;
  __syncthreads();
  for (int off = 1; off < 256; off <<= 1) {
    int u = (t >= off) ? lds[t - off] : 0;
    __syncthreads();
    val += u;
    lds[t] = val;
    __syncthreads();
  }
  int excl = val - tsum;
#pragma unroll
  for (int j = 0; j < 4; ++j) {
    int idx = idx0 + j;
    if (idx < N_NODES) offs[idx] = excl;
    excl += c[j];
  }
  if (t == 255) bsum[blockIdx.x] = val;
}

__global__ __launch_bounds__(128) void k_scan2(int* __restrict__ bsum, int nblk) {
  __shared__ int lds[128];
  int t = threadIdx.x;
  int orig = (t < nblk) ? bsum[t] : 0;
  int val = orig;
  lds[t] = val;
  __syncthreads();
  for (int off = 1; off < 128; off <<= 1) {
    int u = (t >= off) ? lds[t - off] : 0;
    __syncthreads();
    val += u;
    lds[t] = val;
    __syncthreads();
  }
  if (t < nblk) bsum[t] = val - orig;
}

// finalize offs, seed bucket cursors bcur[b] = offs[128*b], set offs[N]=E
__global__ __launch_bounds__(256) void k_scan3(int* __restrict__ offs,
                                               int* __restrict__ bcur,
                                               const int* __restrict__ bsum) {
  int t = threadIdx.x;
  int add = bsum[blockIdx.x];
  int idx0 = blockIdx.x * 1024 + t * 4;
#pragma unroll
  for (int j = 0; j < 4; ++j) {
    int idx = idx0 + j;
    if (idx < N_NODES) {
      int v = offs[idx] + add;
      offs[idx] = v;
      if ((idx & 127) == 0) bcur[idx >> 7] = v;
    }
  }
  if (blockIdx.x == 0 && t == 0) offs[N_NODES] = N_EDGES;
}

// ---------------- phase A: bin edges into buckets of 128 nodes ----------------
// Block-local LDS counts -> one global atomicAdd per (block,bucket) -> writes
// each bucket's edges as a contiguous ~84B chunk (coalesced-ish, no 64B-line churn).
__global__ __launch_bounds__(256) void k_partition(const int* __restrict__ ei,
                                                   int* __restrict__ bcur,
                                                   int2* __restrict__ pairs) {
  __shared__ int cnt[NB];
  __shared__ int base[NB];
  for (int b = threadIdx.x; b < NB; b += 256) cnt[b] = 0;
  __syncthreads();
  int e0 = blockIdx.x * 8192;
  int eend = min(e0 + 8192, N_EDGES);
  for (int e = e0 + threadIdx.x; e < eend; e += 256) {
    int d = ei[N_EDGES + e];
    atomicAdd(&cnt[d >> 7], 1);
  }
  __syncthreads();
  for (int b = threadIdx.x; b < NB; b += 256) {
    int c = cnt[b];
    base[b] = c ? atomicAdd(&bcur[b], c) : 0;
    cnt[b] = 0;
  }
  __syncthreads();
  for (int e = e0 + threadIdx.x; e < eend; e += 256) {
    int s = ei[e];
    int d = ei[N_EDGES + e];
    int b = d >> 7;
    int r = atomicAdd(&cnt[b], 1);
    pairs[base[b] + r] = make_int2(s, d);
  }
}

// ---------------- phase B: within-bucket CSR fill (scatter in a 16KB L2 window) ----
__global__ __launch_bounds__(256) void k_bucket_csr(const int2* __restrict__ pairs,
                                                    const int* __restrict__ offs,
                                                    int* __restrict__ csr) {
  __shared__ int lcur[128];
  int node0 = blockIdx.x << 7;
  int nloc = min(128, N_NODES - node0);
  if (threadIdx.x < nloc) lcur[threadIdx.x] = offs[node0 + threadIdx.x];
  __syncthreads();
  int beg = offs[node0];
  int end = offs[min(node0 + 128, N_NODES)];
  for (int i = beg + threadIdx.x; i < end; i += 256) {
    int2 p = pairs[i];
    int pos = atomicAdd(&lcur[p.y - node0], 1);
    csr[pos] = p.x;
  }
}

// ---------------- weight prep (all 4 weights in one launch) ----------------
__device__ __forceinline__ void split_one(const float* W, _Float16* hi, _Float16* lo,
                                          int K, int i) {
  int k = i >> 6, n = i & 63;
  float v = W[i];
  _Float16 h = (_Float16)v;
  float r = v - (float)h;
  hi[n * K + k] = h;
  lo[n * K + k] = (_Float16)r;
}

__global__ __launch_bounds__(256) void k_prep_all(
    const float* __restrict__ Wp, const float* __restrict__ W1,
    const float* __restrict__ W2, const float* __restrict__ W3,
    _Float16* __restrict__ WpH, _Float16* __restrict__ WpL,
    _Float16* __restrict__ W1H, _Float16* __restrict__ W1L,
    _Float16* __restrict__ W2H, _Float16* __restrict__ W2L,
    _Float16* __restrict__ W3H, _Float16* __restrict__ W3L) {
  int blk = blockIdx.x;
  if (blk < 32) split_one(Wp, WpH, WpL, IN_DIM, blk * 256 + threadIdx.x);
  else if (blk < 48) split_one(W1, W1H, W1L, HID, (blk - 32) * 256 + threadIdx.x);
  else if (blk < 64) split_one(W2, W2H, W2L, HID, (blk - 48) * 256 + threadIdx.x);
  else split_one(W3, W3H, W3L, HID, (blk - 64) * 256 + threadIdx.x);
}

// ---------------- MFMA GEMM: [N,K] fp32 @ Wt(half hi/lo) -> [N,64] fp32 ------------
template <int K, bool BIAS>
__global__ __launch_bounds__(256) void k_gemm_mfma(const float* __restrict__ X,
                                                   const _Float16* __restrict__ Wh,
                                                   const _Float16* __restrict__ Wl,
                                                   const float* __restrict__ bias,
                                                   float* __restrict__ out) {
  int wave = threadIdx.x >> 6;
  int lane = threadIdx.x & 63;
  int fi = lane & 15;
  int quad = lane >> 4;
  int r0 = blockIdx.x * 64 + wave * 16;
  int row_l = r0 + fi;
  if (row_l >= N_NODES) row_l = N_NODES - 1;
  const float* xp = X + (size_t)row_l * K + quad * 8;

  f4v acc[4];
#pragma unroll
  for (int ct = 0; ct < 4; ++ct) acc[ct] = (f4v){0.f, 0.f, 0.f, 0.f};

#pragma unroll
  for (int k0 = 0; k0 < K; k0 += 32) {
    f4v xa = *(const f4v*)(xp + k0);
    f4v xb = *(const f4v*)(xp + k0 + 4);
    h8v ah, al;
#pragma unroll
    for (int j = 0; j < 4; ++j) {
      _Float16 h = (_Float16)xa[j];
      ah[j] = h;
      al[j] = (_Float16)(xa[j] - (float)h);
    }
#pragma unroll
    for (int j = 0; j < 4; ++j) {
      _Float16 h = (_Float16)xb[j];
      ah[4 + j] = h;
      al[4 + j] = (_Float16)(xb[j] - (float)h);
    }
    const _Float16* whp = Wh + (size_t)fi * K + k0 + quad * 8;
    const _Float16* wlp = Wl + (size_t)fi * K + k0 + quad * 8;
#pragma unroll
    for (int ct = 0; ct < 4; ++ct) {
      h8v bh = *(const h8v*)(whp + (size_t)ct * 16 * K);
      h8v bl = *(const h8v*)(wlp + (size_t)ct * 16 * K);
      acc[ct] = __builtin_amdgcn_mfma_f32_16x16x32_f16(ah, bh, acc[ct], 0, 0, 0);
      acc[ct] = __builtin_amdgcn_mfma_f32_16x16x32_f16(al, bh, acc[ct], 0, 0, 0);
      acc[ct] = __builtin_amdgcn_mfma_f32_16x16x32_f16(ah, bl, acc[ct], 0, 0, 0);
    }
  }

#pragma unroll
  for (int ct = 0; ct < 4; ++ct) {
    float bv = 0.f;
    if (BIAS) bv = bias[ct * 16 + fi];
#pragma unroll
    for (int j = 0; j < 4; ++j) {
      int orow = r0 + quad * 4 + j;
      if (orow < N_NODES) out[(size_t)orow * HID + ct * 16 + fi] = acc[ct][j] + bv;
    }
  }
}

// ---------------- aggregation: wave per node, 16 gathers in flight -------
// MODE 0: bias + relu      MODE 1: bias + L2 row-normalize (final layer)
template <int MODE>
__global__ __launch_bounds__(256) void k_agg(const float* __restrict__ hw,
                                             const int* __restrict__ offs,
                                             const int* __restrict__ csr,
                                             const float* __restrict__ dinv,
                                             const float* __restrict__ bias,
                                             float* __restrict__ out) {
  int node = blockIdx.x * 4 + (threadIdx.x >> 6);
  int lane = threadIdx.x & 63;
  int quad = lane >> 4;
  int fi = lane & 15;
  float di = dinv[node];
  int beg = offs[node];
  int end = offs[node + 1];

  f4v acc = {0.f, 0.f, 0.f, 0.f};
  if (quad == 0) {
    f4v hv = *(const f4v*)(hw + (size_t)node * HID + fi * 4);
    acc = hv * (di * di);
  }
  // predicated 4-deep unroll per quad: 16 neighbor-row gathers in flight/wave.
  // invalid slots clamp to the node's own (hot) row with weight 0.
  for (int e0 = beg + quad; e0 < end; e0 += 16) {
    int ss[4];
    float ww[4];
#pragma unroll
    for (int j = 0; j < 4; ++j) {
      int e = e0 + 4 * j;
      bool v = e < end;
      int s = csr[v ? e : beg];
      ss[j] = v ? s : node;
      ww[j] = v ? di : 0.0f;
    }
#pragma unroll
    for (int j = 0; j < 4; ++j) ww[j] *= dinv[ss[j]];
    f4v hv[4];
#pragma unroll
    for (int j = 0; j < 4; ++j)
      hv[j] = *(const f4v*)(hw + (size_t)ss[j] * HID + fi * 4);
#pragma unroll
    for (int j = 0; j < 4; ++j) acc += hv[j] * ww[j];
  }
  // reduce across the 4 quads
#pragma unroll
  for (int c = 0; c < 4; ++c) {
    float v = acc[c];
    v += __shfl_xor(v, 16);
    v += __shfl_xor(v, 32);
    acc[c] = v;
  }
  if (quad == 0) {
    f4v bv = *(const f4v*)(bias + fi * 4);
    acc += bv;
    if (MODE == 0) {
#pragma unroll
      for (int c = 0; c < 4; ++c) acc[c] = fmaxf(acc[c], 0.f);
    } else {
      float ss = acc[0] * acc[0] + acc[1] * acc[1] + acc[2] * acc[2] + acc[3] * acc[3];
      ss += __shfl_xor(ss, 1);
      ss += __shfl_xor(ss, 2);
      ss += __shfl_xor(ss, 4);
      ss += __shfl_xor(ss, 8);
      float sc = 1.0f / fmaxf(sqrtf(ss), 1e-12f);
      acc *= sc;
    }
    *(f4v*)(out + (size_t)node * HID + fi * 4) = acc;
  }
}

extern "C" void kernel_launch(void* const* d_in, const int* in_sizes, int n_in,
                              void* d_out, int out_size, void* d_ws, size_t ws_size,
                              hipStream_t stream) {
  const float* x     = (const float*)d_in[0];
  const int*   ei    = (const int*)d_in[1];   // [2, E] int32
  const float* W_pre = (const float*)d_in[2];
  const float* b_pre = (const float*)d_in[3];
  const float* W1    = (const float*)d_in[4];
  const float* b1    = (const float*)d_in[5];
  const float* W2    = (const float*)d_in[6];
  const float* b2    = (const float*)d_in[7];
  const float* W3    = (const float*)d_in[8];
  const float* b3    = (const float*)d_in[9];
  float* out = (float*)d_out;

  char* ws = (char*)d_ws;
  float* bufA   = (float*)(ws + 0);                // 25.6 MB features
  int2*  pairs  = (int2*)(ws + 0);                 // 12.8 MB, aliases bufA (dead until pre_gemm)
  float* hw     = (float*)(ws + 25600000);         // 25.6 MB gemm out
  int*   csr    = (int*)(ws + 51200000);           // 6.4 MB
  int*   counts = (int*)(ws + 57600000);           // 400 KB
  int*   offs   = (int*)(ws + 58000000);           // N+1 ints
  float* dinv   = (float*)(ws + 58400016);         // 400 KB
  int*   bsum   = (int*)(ws + 58800016);           // scan partials (512 B)
  int*   bcur   = (int*)(ws + 58800528);           // NB ints (3128 B)
  _Float16* WpreH = (_Float16*)(ws + 58810000);    // 16 KB
  _Float16* WpreL = (_Float16*)(ws + 58826384);
  _Float16* W1H   = (_Float16*)(ws + 58842768);    // 8 KB each
  _Float16* W1L   = (_Float16*)(ws + 58850960);
  _Float16* W2H   = (_Float16*)(ws + 58859152);
  _Float16* W2L   = (_Float16*)(ws + 58867344);
  _Float16* W3H   = (_Float16*)(ws + 58875536);
  _Float16* W3L   = (_Float16*)(ws + 58883728);

  const int NBLK = (N_NODES + 1023) / 1024;        // 98
  const int GEMM_BLOCKS = (N_NODES + 63) / 64;     // 1563
  const int PART_BLOCKS = (N_EDGES + 8191) / 8192; // 196

  hipMemsetAsync(counts, 0, N_NODES * sizeof(int), stream);
  k_hist<<<(N_EDGES + 255) / 256, 256, 0, stream>>>(ei + N_EDGES, counts);
  k_dinv<<<(N_NODES + 255) / 256, 256, 0, stream>>>(counts, dinv);
  k_scan1<<<NBLK, 256, 0, stream>>>(counts, offs, bsum);
  k_scan2<<<1, 128, 0, stream>>>(bsum, NBLK);
  k_scan3<<<NBLK, 256, 0, stream>>>(offs, bcur, bsum);
  k_partition<<<PART_BLOCKS, 256, 0, stream>>>(ei, bcur, pairs);
  k_bucket_csr<<<NB, 256, 0, stream>>>(pairs, offs, csr);

  k_prep_all<<<80, 256, 0, stream>>>(W_pre, W1, W2, W3, WpreH, WpreL,
                                     W1H, W1L, W2H, W2L, W3H, W3L);

  k_gemm_mfma<IN_DIM, true><<<GEMM_BLOCKS, 256, 0, stream>>>(x, WpreH, WpreL, b_pre, bufA);

  // layer 1
  k_gemm_mfma<HID, false><<<GEMM_BLOCKS, 256, 0, stream>>>(bufA, W1H, W1L, nullptr, hw);
  k_agg<0><<<N_NODES / 4, 256, 0, stream>>>(hw, offs, csr, dinv, b1, bufA);
  // layer 2
  k_gemm_mfma<HID, false><<<GEMM_BLOCKS, 256, 0, stream>>>(bufA, W2H, W2L, nullptr, hw);
  k_agg<0><<<N_NODES / 4, 256, 0, stream>>>(hw, offs, csr, dinv, b2, bufA);
  // layer 3 (fused L2 normalize)
  k_gemm_mfma<HID, false><<<GEMM_BLOCKS, 256, 0, stream>>>(bufA, W3H, W3L, nullptr, hw);
  k_agg<1><<<N_NODES / 4, 256, 0, stream>>>(hw, offs, csr, dinv, b3, out);
}

// Round 5
// 386.118 us; speedup vs baseline: 2.6013x; 1.2999x over previous
//
#include <hip/hip_runtime.h>
#include <hip/hip_bf16.h>

#define N_NODES 100000
#define N_EDGES 1600000
#define IN_DIM 128
#define HID 64
#define NB 782               // ceil(100000 / 128) buckets of 128 nodes

typedef __attribute__((ext_vector_type(8))) _Float16 h8v;
typedef __attribute__((ext_vector_type(4))) float f4v;

// ---------------- bucket histogram (782 buckets, LDS-aggregated) ----------------
__global__ __launch_bounds__(256) void k_bhist(const int* __restrict__ dst,
                                               int* __restrict__ bsz) {
  __shared__ int cnt[NB];
  for (int b = threadIdx.x; b < NB; b += 256) cnt[b] = 0;
  __syncthreads();
  int e0 = blockIdx.x * 8192;
  int eend = min(e0 + 8192, N_EDGES);
  for (int e = e0 + threadIdx.x; e < eend; e += 256)
    atomicAdd(&cnt[dst[e] >> 7], 1);
  __syncthreads();
  for (int b = threadIdx.x; b < NB; b += 256)
    if (cnt[b]) atomicAdd(&bsz[b], cnt[b]);
}

// ---------------- bucket scan: bboff = exclusive scan(bsz); bcur = copy --------
__global__ __launch_bounds__(1024) void k_bscan(const int* __restrict__ bsz,
                                                int* __restrict__ bboff,
                                                int* __restrict__ bcur) {
  __shared__ int sc[1024];
  int t = threadIdx.x;
  int v = (t < NB) ? bsz[t] : 0;
  sc[t] = v;
  __syncthreads();
  for (int off = 1; off < 1024; off <<= 1) {
    int u = (t >= off) ? sc[t - off] : 0;
    __syncthreads();
    sc[t] += u;
    __syncthreads();
  }
  if (t < NB) {
    int excl = sc[t] - v;
    bboff[t] = excl;
    bcur[t] = excl;
    if (t == NB - 1) bboff[NB] = excl + v;  // == N_EDGES
  }
}

// ---------------- phase A: bin edges into buckets of 128 nodes ----------------
__global__ __launch_bounds__(256) void k_partition(const int* __restrict__ ei,
                                                   int* __restrict__ bcur,
                                                   int2* __restrict__ pairs) {
  __shared__ int cnt[NB];
  __shared__ int base[NB];
  for (int b = threadIdx.x; b < NB; b += 256) cnt[b] = 0;
  __syncthreads();
  int e0 = blockIdx.x * 8192;
  int eend = min(e0 + 8192, N_EDGES);
  for (int e = e0 + threadIdx.x; e < eend; e += 256) {
    int d = ei[N_EDGES + e];
    atomicAdd(&cnt[d >> 7], 1);
  }
  __syncthreads();
  for (int b = threadIdx.x; b < NB; b += 256) {
    int c = cnt[b];
    base[b] = c ? atomicAdd(&bcur[b], c) : 0;
    cnt[b] = 0;
  }
  __syncthreads();
  for (int e = e0 + threadIdx.x; e < eend; e += 256) {
    int s = ei[e];
    int d = ei[N_EDGES + e];
    int b = d >> 7;
    int r = atomicAdd(&cnt[b], 1);
    pairs[base[b] + r] = make_int2(s, d);
  }
}

// ---------------- phase B: per-bucket degrees + offs + dinv + CSR scatter -------
__global__ __launch_bounds__(256) void k_csr_deg(const int2* __restrict__ pairs,
                                                 const int* __restrict__ bboff,
                                                 int* __restrict__ offs,
                                                 float* __restrict__ dinv,
                                                 int* __restrict__ csr) {
  __shared__ int ldeg[128];
  __shared__ int sc[128];
  __shared__ int lcur[128];
  int t = threadIdx.x;
  int node0 = blockIdx.x << 7;
  int nloc = min(128, N_NODES - node0);
  int beg = bboff[blockIdx.x];
  int end = bboff[blockIdx.x + 1];
  if (t < 128) ldeg[t] = 0;
  __syncthreads();
  for (int i = beg + t; i < end; i += 256)
    atomicAdd(&ldeg[pairs[i].y - node0], 1);
  __syncthreads();
  int dv = (t < 128) ? ldeg[t] : 0;
  if (t < 128) sc[t] = dv;
  __syncthreads();
  for (int off = 1; off < 128; off <<= 1) {
    int u = (t >= off && t < 128) ? sc[t - off] : 0;
    __syncthreads();
    if (t < 128) sc[t] += u;
    __syncthreads();
  }
  if (t < nloc) {
    int excl = sc[t] - dv;
    int o = beg + excl;
    offs[node0 + t] = o;
    lcur[t] = o;
    dinv[node0 + t] = rsqrtf((float)dv + 1.0f);
  }
  if (blockIdx.x == NB - 1 && t == 0) offs[N_NODES] = N_EDGES;
  __syncthreads();
  for (int i = beg + t; i < end; i += 256) {
    int2 p = pairs[i];
    int pos = atomicAdd(&lcur[p.y - node0], 1);
    csr[pos] = p.x;
  }
}

// ---------------- weight prep (all 4 weights in one launch) ----------------
__device__ __forceinline__ void split_one(const float* W, _Float16* hi, _Float16* lo,
                                          int K, int i) {
  int k = i >> 6, n = i & 63;
  float v = W[i];
  _Float16 h = (_Float16)v;
  float r = v - (float)h;
  hi[n * K + k] = h;
  lo[n * K + k] = (_Float16)r;
}

__global__ __launch_bounds__(256) void k_prep_all(
    const float* __restrict__ Wp, const float* __restrict__ W1,
    const float* __restrict__ W2, const float* __restrict__ W3,
    _Float16* __restrict__ WpH, _Float16* __restrict__ WpL,
    _Float16* __restrict__ W1H, _Float16* __restrict__ W1L,
    _Float16* __restrict__ W2H, _Float16* __restrict__ W2L,
    _Float16* __restrict__ W3H, _Float16* __restrict__ W3L) {
  int blk = blockIdx.x;
  if (blk < 32) split_one(Wp, WpH, WpL, IN_DIM, blk * 256 + threadIdx.x);
  else if (blk < 48) split_one(W1, W1H, W1L, HID, (blk - 32) * 256 + threadIdx.x);
  else if (blk < 64) split_one(W2, W2H, W2L, HID, (blk - 48) * 256 + threadIdx.x);
  else split_one(W3, W3H, W3L, HID, (blk - 64) * 256 + threadIdx.x);
}

// ---------------- MFMA GEMM: [N,K] fp32 @ Wt(half hi/lo) -> [N,64] OutT ------------
template <int K, bool BIAS, typename OutT>
__global__ __launch_bounds__(256) void k_gemm_mfma(const float* __restrict__ X,
                                                   const _Float16* __restrict__ Wh,
                                                   const _Float16* __restrict__ Wl,
                                                   const float* __restrict__ bias,
                                                   OutT* __restrict__ out) {
  int wave = threadIdx.x >> 6;
  int lane = threadIdx.x & 63;
  int fi = lane & 15;
  int quad = lane >> 4;
  int r0 = blockIdx.x * 64 + wave * 16;
  int row_l = r0 + fi;
  if (row_l >= N_NODES) row_l = N_NODES - 1;
  const float* xp = X + (size_t)row_l * K + quad * 8;

  f4v acc[4];
#pragma unroll
  for (int ct = 0; ct < 4; ++ct) acc[ct] = (f4v){0.f, 0.f, 0.f, 0.f};

#pragma unroll
  for (int k0 = 0; k0 < K; k0 += 32) {
    f4v xa = *(const f4v*)(xp + k0);
    f4v xb = *(const f4v*)(xp + k0 + 4);
    h8v ah, al;
#pragma unroll
    for (int j = 0; j < 4; ++j) {
      _Float16 h = (_Float16)xa[j];
      ah[j] = h;
      al[j] = (_Float16)(xa[j] - (float)h);
    }
#pragma unroll
    for (int j = 0; j < 4; ++j) {
      _Float16 h = (_Float16)xb[j];
      ah[4 + j] = h;
      al[4 + j] = (_Float16)(xb[j] - (float)h);
    }
    const _Float16* whp = Wh + (size_t)fi * K + k0 + quad * 8;
    const _Float16* wlp = Wl + (size_t)fi * K + k0 + quad * 8;
#pragma unroll
    for (int ct = 0; ct < 4; ++ct) {
      h8v bh = *(const h8v*)(whp + (size_t)ct * 16 * K);
      h8v bl = *(const h8v*)(wlp + (size_t)ct * 16 * K);
      acc[ct] = __builtin_amdgcn_mfma_f32_16x16x32_f16(ah, bh, acc[ct], 0, 0, 0);
      acc[ct] = __builtin_amdgcn_mfma_f32_16x16x32_f16(al, bh, acc[ct], 0, 0, 0);
      acc[ct] = __builtin_amdgcn_mfma_f32_16x16x32_f16(ah, bl, acc[ct], 0, 0, 0);
    }
  }

#pragma unroll
  for (int ct = 0; ct < 4; ++ct) {
    float bv = 0.f;
    if (BIAS) bv = bias[ct * 16 + fi];
#pragma unroll
    for (int j = 0; j < 4; ++j) {
      int orow = r0 + quad * 4 + j;
      if (orow < N_NODES) out[(size_t)orow * HID + ct * 16 + fi] = (OutT)(acc[ct][j] + bv);
    }
  }
}

// ---------------- aggregation: wave per node, oct-parallel fp16 gather -------
// 8 rows in flight x 2-deep unroll = 16 gathers; 16 B (8 halfs) per lane.
// MODE 0: bias + relu      MODE 1: bias + L2 row-normalize (final layer)
template <int MODE>
__global__ __launch_bounds__(256) void k_agg(const _Float16* __restrict__ hw,
                                             const int* __restrict__ offs,
                                             const int* __restrict__ csr,
                                             const float* __restrict__ dinv,
                                             const float* __restrict__ bias,
                                             float* __restrict__ out) {
  int node = blockIdx.x * 4 + (threadIdx.x >> 6);
  int lane = threadIdx.x & 63;
  int oct = lane >> 3;       // 8 row-slots
  int fi = lane & 7;         // 8 halfs (16 B) of the 64-feature row
  float di = dinv[node];
  int beg = offs[node];
  int end = offs[node + 1];

  float acc[8];
#pragma unroll
  for (int c = 0; c < 8; ++c) acc[c] = 0.f;

  if (oct == 0) {  // self-loop term
    h8v hv = *(const h8v*)(hw + (size_t)node * HID + fi * 8);
    float w = di * di;
#pragma unroll
    for (int c = 0; c < 8; ++c) acc[c] += (float)hv[c] * w;
  }
  for (int e0 = beg + oct; e0 < end; e0 += 16) {
    int ss[2];
    float ww[2];
#pragma unroll
    for (int j = 0; j < 2; ++j) {
      int e = e0 + 8 * j;
      bool v = e < end;
      int s = csr[v ? e : beg];
      ss[j] = v ? s : node;
      ww[j] = v ? di : 0.0f;
    }
#pragma unroll
    for (int j = 0; j < 2; ++j) ww[j] *= dinv[ss[j]];
    h8v hv[2];
#pragma unroll
    for (int j = 0; j < 2; ++j)
      hv[j] = *(const h8v*)(hw + (size_t)ss[j] * HID + fi * 8);
#pragma unroll
    for (int j = 0; j < 2; ++j)
#pragma unroll
      for (int c = 0; c < 8; ++c) acc[c] += (float)hv[j][c] * ww[j];
  }
  // reduce across the 8 octs
#pragma unroll
  for (int c = 0; c < 8; ++c) {
    float v = acc[c];
    v += __shfl_xor(v, 8);
    v += __shfl_xor(v, 16);
    v += __shfl_xor(v, 32);
    acc[c] = v;
  }
  if (oct == 0) {
#pragma unroll
    for (int c = 0; c < 8; ++c) acc[c] += bias[fi * 8 + c];
    if (MODE == 0) {
#pragma unroll
      for (int c = 0; c < 8; ++c) acc[c] = fmaxf(acc[c], 0.f);
    } else {
      float ss = 0.f;
#pragma unroll
      for (int c = 0; c < 8; ++c) ss += acc[c] * acc[c];
      ss += __shfl_xor(ss, 1);
      ss += __shfl_xor(ss, 2);
      ss += __shfl_xor(ss, 4);
      float sc = 1.0f / fmaxf(sqrtf(ss), 1e-12f);
#pragma unroll
      for (int c = 0; c < 8; ++c) acc[c] *= sc;
    }
    f4v o0 = {acc[0], acc[1], acc[2], acc[3]};
    f4v o1 = {acc[4], acc[5], acc[6], acc[7]};
    *(f4v*)(out + (size_t)node * HID + fi * 8) = o0;
    *(f4v*)(out + (size_t)node * HID + fi * 8 + 4) = o1;
  }
}

extern "C" void kernel_launch(void* const* d_in, const int* in_sizes, int n_in,
                              void* d_out, int out_size, void* d_ws, size_t ws_size,
                              hipStream_t stream) {
  const float* x     = (const float*)d_in[0];
  const int*   ei    = (const int*)d_in[1];   // [2, E] int32
  const float* W_pre = (const float*)d_in[2];
  const float* b_pre = (const float*)d_in[3];
  const float* W1    = (const float*)d_in[4];
  const float* b1    = (const float*)d_in[5];
  const float* W2    = (const float*)d_in[6];
  const float* b2    = (const float*)d_in[7];
  const float* W3    = (const float*)d_in[8];
  const float* b3    = (const float*)d_in[9];
  float* out = (float*)d_out;

  char* ws = (char*)d_ws;
  float*    bufA  = (float*)(ws + 0);              // 25.6 MB fp32 features
  int2*     pairs = (int2*)(ws + 0);               // 12.8 MB, aliases bufA (dead before pre_gemm)
  _Float16* hw16  = (_Float16*)(ws + 25600000);    // 12.8 MB fp16 gemm out
  int*      csr   = (int*)(ws + 38400000);         // 6.4 MB
  int*      offs  = (int*)(ws + 44800000);         // (N+1) ints
  float*    dinv  = (float*)(ws + 45200016);       // 400 KB
  int*      bsz   = (int*)(ws + 45600016);         // NB ints
  int*      bboff = (int*)(ws + 45603200);         // NB+1 ints
  int*      bcur  = (int*)(ws + 45606400);         // NB ints
  _Float16* WpreH = (_Float16*)(ws + 45610000);    // 16 KB
  _Float16* WpreL = (_Float16*)(ws + 45626384);
  _Float16* W1H   = (_Float16*)(ws + 45642768);    // 8 KB each
  _Float16* W1L   = (_Float16*)(ws + 45650960);
  _Float16* W2H   = (_Float16*)(ws + 45659152);
  _Float16* W2L   = (_Float16*)(ws + 45667344);
  _Float16* W3H   = (_Float16*)(ws + 45675536);
  _Float16* W3L   = (_Float16*)(ws + 45683728);

  const int GEMM_BLOCKS = (N_NODES + 63) / 64;     // 1563
  const int PART_BLOCKS = (N_EDGES + 8191) / 8192; // 196

  hipMemsetAsync(bsz, 0, NB * sizeof(int), stream);
  k_bhist<<<PART_BLOCKS, 256, 0, stream>>>(ei + N_EDGES, bsz);
  k_bscan<<<1, 1024, 0, stream>>>(bsz, bboff, bcur);
  k_partition<<<PART_BLOCKS, 256, 0, stream>>>(ei, bcur, pairs);
  k_csr_deg<<<NB, 256, 0, stream>>>(pairs, bboff, offs, dinv, csr);

  k_prep_all<<<80, 256, 0, stream>>>(W_pre, W1, W2, W3, WpreH, WpreL,
                                     W1H, W1L, W2H, W2L, W3H, W3L);

  k_gemm_mfma<IN_DIM, true, float><<<GEMM_BLOCKS, 256, 0, stream>>>(x, WpreH, WpreL, b_pre, bufA);

  // layer 1
  k_gemm_mfma<HID, false, _Float16><<<GEMM_BLOCKS, 256, 0, stream>>>(bufA, W1H, W1L, nullptr, hw16);
  k_agg<0><<<N_NODES / 4, 256, 0, stream>>>(hw16, offs, csr, dinv, b1, bufA);
  // layer 2
  k_gemm_mfma<HID, false, _Float16><<<GEMM_BLOCKS, 256, 0, stream>>>(bufA, W2H, W2L, nullptr, hw16);
  k_agg<0><<<N_NODES / 4, 256, 0, stream>>>(hw16, offs, csr, dinv, b2, bufA);
  // layer 3 (fused L2 normalize)
  k_gemm_mfma<HID, false, _Float16><<<GEMM_BLOCKS, 256, 0, stream>>>(bufA, W3H, W3L, nullptr, hw16);
  k_agg<1><<<N_NODES / 4, 256, 0, stream>>>(hw16, offs, csr, dinv, b3, out);
}